// Round 7
// baseline (194.894 us; speedup 1.0000x reference)
//
#include <hip/hip_runtime.h>
#include <hip/hip_fp16.h>

#define LOG2E 1.44269504088896340736f
#define DM 1536
#define LL  2048
#define NN  16
#define NCH 64     // chunks per row = lanes per wave
#define CL  32     // LL / NCH
#define SL  (NCH*NN)   // slab stride per step (floats)

typedef float v4f __attribute__((ext_vector_type(4)));

__device__ __forceinline__ float fexp2(float v){ return __builtin_amdgcn_exp2f(v); }
__device__ __forceinline__ float frcp(float v){ return __builtin_amdgcn_rcpf(v); }

__device__ __forceinline__ v4f ntload4(const float* p){
    return __builtin_nontemporal_load((const v4f*)p);
}
__device__ __forceinline__ void ntstore4(float* p, v4f v){
    __builtin_nontemporal_store(v, (v4f*)p);
}

__device__ __forceinline__ void load16(const float* __restrict__ p, float* v){
    const float4 a=*(const float4*)p,     b=*(const float4*)(p+4),
                 c=*(const float4*)(p+8), d=*(const float4*)(p+12);
    v[0]=a.x; v[1]=a.y; v[2]=a.z; v[3]=a.w;
    v[4]=b.x; v[5]=b.y; v[6]=b.z; v[7]=b.w;
    v[8]=c.x; v[9]=c.y; v[10]=c.z; v[11]=c.w;
    v[12]=d.x; v[13]=d.y; v[14]=d.z; v[15]=d.w;
}

__device__ __forceinline__ float packdx(float d, float x){
    unsigned u = (unsigned)__half_as_ushort(__float2half_rn(d))
               | ((unsigned)__half_as_ushort(__float2half_rn(x)) << 16);
    return __uint_as_float(u);
}
__device__ __forceinline__ void unpackdx(float f, float& d, float& x){
    const unsigned u = __float_as_uint(f);
    d = __half2float(__ushort_as_half((unsigned short)(u & 0xffffu)));
    x = __half2float(__ushort_as_half((unsigned short)(u >> 16)));
}

// B,C: [b][n][t] -> Bt[((b*32 + (t&31))*64 + (t>>5))*16 + n]
// nt reads (stream-once); cached writes (consumed by ssm_scan from L2).
__global__ __launch_bounds__(256) void transpose_bc(
        const float* __restrict__ Bm, const float* __restrict__ Cm,
        float* __restrict__ Bt, float* __restrict__ Ct){
    const int q  = blockIdx.x*256 + threadIdx.x;   // 16384 float4 quads
    const int t0 = (q & 511) << 2;
    const int n  = (q >> 9) & 15;
    const int b  = q >> 13;
    const long i = (long)(b*NN + n)*LL + t0;
    const v4f bv = ntload4(Bm + i);
    const v4f cv = ntload4(Cm + i);
#pragma unroll
    for (int j=0;j<4;++j){
        const int t = t0 + j;
        const int o = ((b*CL + (t&31))*NCH + (t>>5))*NN + n;
        Bt[o] = bv[j];
        Ct[o] = cv[j];
    }
}

// Block = 4 waves, wave = one (b,d) row; lane = chunk (64 x 32 steps);
// thread owns all 16 states. (delta,x) in LDS as packed half2, XOR-swizzled.
// Streams (delta,x,z,out) are NONTEMPORAL so the 512 KB Bt/Ct slab set stays
// L2-resident (theory: streaming traffic was evicting it -> per-step L3-class
// latency). Hot loops: explicit 2-buffer, branch-free steady state, dist-1
// prefetch of B/C slabs and of the next packed LDS word.
__global__ __launch_bounds__(256, 3) void ssm_scan(
    const float* __restrict__ x, const float* __restrict__ delta,
    const float* __restrict__ A, const float* __restrict__ Dv,
    const float* __restrict__ z, const float* __restrict__ Bt,
    const float* __restrict__ Ct, float* __restrict__ out)
{
    __shared__ float sdx[4][CL*64];  // packed half2{delta,x}; fp32 (y+x*D) after phase 3

    const int lane = threadIdx.x & 63;
    const int w    = threadIdx.x >> 6;
    const int row  = blockIdx.x*4 + w;           // b*DM + d
    const int b    = (row >= DM) ? 1 : 0;
    const int d    = row - b*DM;
    float* sw = sdx[w];

    const long base = (long)row*LL;
    const float* gd = delta + base;
    const float* gx = x + base;

    // ---- stage packed (delta,x): nt float4 reads, 2-way-banked LDS writes
    for (int k=0;k<LL;k+=256){
        const int t0 = k + lane*4;
        const v4f dv = ntload4(gd + t0);
        const v4f xv = ntload4(gx + t0);
#pragma unroll
        for (int j=0;j<4;++j){
            const int t = t0 + j, r = t & 31, c = t >> 5;
            sw[r*64 + (c^r)] = packdx(dv[j], xv[j]);
        }
    }

    float A2[NN];
#pragma unroll
    for (int n=0;n<NN;++n) A2[n] = A[d*NN+n] * LOG2E;   // exp(dA)=exp2(d*A2)

    const float* bq = Bt + (long)b*(CL*SL) + lane*NN;   // + r*SL per step
    const float* cq = Ct + (long)b*(CL*SL) + lane*NN;

    // ---- phase 1: local scan h0=0 -> G; P = exp2(A2 * sum(delta))
    float G[NN];
#pragma unroll
    for (int n=0;n<NN;++n) G[n] = 0.f;
    float dsum = 0.f;

    auto step1 = [&](float pk, const float* bb){
        float d_r, x_r;
        unpackdx(pk, d_r, x_r);
        dsum += d_r;
        const float dx = d_r * x_r;
#pragma unroll
        for (int n=0;n<NN;++n){
            const float e = fexp2(d_r*A2[n]);
            G[n] = __builtin_fmaf(e, G[n], bb[n]*dx);
        }
    };

    {
        float b0[NN], b1[NN];
        load16(bq, b0);
        float p0 = sw[lane];   // r=0: slot 0*64 + (lane^0)
        float p1;
#pragma unroll 2
        for (int r=0;r<CL;r+=2){
            load16(bq + (r+1)*SL, b1);
            p1 = sw[(r+1)*64 + (lane^(r+1))];
            step1(p0, b0);
            if (r+2 < CL){
                load16(bq + (r+2)*SL, b0);
                p0 = sw[(r+2)*64 + (lane^(r+2))];
            }
            step1(p1, b1);
        }
    }
    float P[NN];
#pragma unroll
    for (int n=0;n<NN;++n) P[n] = fexp2(dsum*A2[n]);

    // ---- phase 2: inclusive Kogge-Stone wave scan over chunks, then shift
#pragma unroll
    for (int s=1;s<64;s<<=1){
#pragma unroll
        for (int n=0;n<NN;++n){
            const float pl = __shfl_up(P[n], s);
            const float gl = __shfl_up(G[n], s);
            if (lane >= s){
                G[n] = __builtin_fmaf(P[n], gl, G[n]);
                P[n] *= pl;
            }
        }
    }
    float h[NN];
#pragma unroll
    for (int n=0;n<NN;++n){
        const float gp = __shfl_up(G[n], 1);
        h[n] = (lane==0) ? 0.f : gp;
    }

    // ---- phase 3: re-scan with true h_start; stash (y + x*D) into LDS slot
    const float Dd = Dv[d];

    auto step3 = [&](int r, float pk, const float* bb, const float* cc){
        float d_r, x_r;
        unpackdx(pk, d_r, x_r);
        const float dx = d_r * x_r;
        float y0=0.f, y1=0.f, y2=0.f, y3=0.f;
#pragma unroll
        for (int n=0;n<NN;n+=4){
            const float e0=fexp2(d_r*A2[n+0]);
            h[n+0]=__builtin_fmaf(e0,h[n+0],bb[n+0]*dx); y0=__builtin_fmaf(h[n+0],cc[n+0],y0);
            const float e1=fexp2(d_r*A2[n+1]);
            h[n+1]=__builtin_fmaf(e1,h[n+1],bb[n+1]*dx); y1=__builtin_fmaf(h[n+1],cc[n+1],y1);
            const float e2=fexp2(d_r*A2[n+2]);
            h[n+2]=__builtin_fmaf(e2,h[n+2],bb[n+2]*dx); y2=__builtin_fmaf(h[n+2],cc[n+2],y2);
            const float e3=fexp2(d_r*A2[n+3]);
            h[n+3]=__builtin_fmaf(e3,h[n+3],bb[n+3]*dx); y3=__builtin_fmaf(h[n+3],cc[n+3],y3);
        }
        const float y = (y0+y1)+(y2+y3);
        sw[r*64 + (lane^r)] = __builtin_fmaf(x_r, Dd, y);  // silu applied later
    };

    {
        float b0[NN], b1[NN], c0[NN], c1[NN];
        load16(bq, b0);
        load16(cq, c0);
        float p0 = sw[lane];
        float p1;
#pragma unroll 2
        for (int r=0;r<CL;r+=2){
            load16(bq + (r+1)*SL, b1);
            load16(cq + (r+1)*SL, c1);
            p1 = sw[(r+1)*64 + (lane^(r+1))];
            step3(r, p0, b0, c0);
            if (r+2 < CL){
                load16(bq + (r+2)*SL, b0);
                load16(cq + (r+2)*SL, c0);
                p0 = sw[(r+2)*64 + (lane^(r+2))];
            }
            step3(r+1, p1, b1, c1);
        }
    }

    // ---- epilogue: stream z once (nt), apply silu, nt float4 stores
    const float* gz = z + base;
    float* go = out + base;
    for (int k=0;k<LL;k+=256){
        const int t0 = k + lane*4;
        const v4f zv = ntload4(gz + t0);
        v4f o4;
#pragma unroll
        for (int j=0;j<4;++j){
            const int t = t0 + j, r = t & 31, c = t >> 5;
            const float yd = sw[r*64 + (c^r)];
            const float zz = zv[j];
            const float sig = frcp(1.f + fexp2(-zz*LOG2E));
            o4[j] = yd * (zz*sig);
        }
        ntstore4(go + t0, o4);
    }
}

extern "C" void kernel_launch(void* const* d_in, const int* in_sizes, int n_in,
                              void* d_out, int out_size, void* d_ws, size_t ws_size,
                              hipStream_t stream) {
    const float* x     = (const float*)d_in[0];
    const float* delta = (const float*)d_in[1];
    const float* A     = (const float*)d_in[2];
    const float* B     = (const float*)d_in[3];
    const float* C     = (const float*)d_in[4];
    const float* Dv    = (const float*)d_in[5];
    const float* z     = (const float*)d_in[6];
    float* out = (float*)d_out;

    float* Bt = (float*)d_ws;                  // 65536 floats = 256 KB
    float* Ct = Bt + 2*LL*NN;                  // next 256 KB

    transpose_bc<<<dim3(64), dim3(256), 0, stream>>>(B, C, Bt, Ct);
    ssm_scan<<<dim3((2*DM)/4), dim3(256), 0, stream>>>(x, delta, A, Dv, z, Bt, Ct, out);
}

// Round 8
// 167.023 us; speedup vs baseline: 1.1669x; 1.1669x over previous
//
#include <hip/hip_runtime.h>
#include <hip/hip_fp16.h>

#define LOG2E 1.44269504088896340736f
#define DM 1536
#define LL  2048
#define NN  16
#define NCH 64     // chunks per row = lanes per wave
#define CL  32     // LL / NCH

__device__ __forceinline__ float fexp2(float v){ return __builtin_amdgcn_exp2f(v); }
__device__ __forceinline__ float frcp(float v){ return __builtin_amdgcn_rcpf(v); }

__device__ __forceinline__ float packdx(float d, float x){
    unsigned u = (unsigned)__half_as_ushort(__float2half_rn(d))
               | ((unsigned)__half_as_ushort(__float2half_rn(x)) << 16);
    return __uint_as_float(u);
}
__device__ __forceinline__ void unpackdx(float f, float& d, float& x){
    const unsigned u = __float_as_uint(f);
    d = __half2float(__ushort_as_half((unsigned short)(u & 0xffffu)));
    x = __half2float(__ushort_as_half((unsigned short)(u >> 16)));
}
// float4 = 8 packed halfs -> 8 floats
__device__ __forceinline__ void unpack8(const float4 f, float* o){
    const unsigned u0=__float_as_uint(f.x), u1=__float_as_uint(f.y),
                   u2=__float_as_uint(f.z), u3=__float_as_uint(f.w);
    o[0]=__half2float(__ushort_as_half((unsigned short)(u0&0xffffu)));
    o[1]=__half2float(__ushort_as_half((unsigned short)(u0>>16)));
    o[2]=__half2float(__ushort_as_half((unsigned short)(u1&0xffffu)));
    o[3]=__half2float(__ushort_as_half((unsigned short)(u1>>16)));
    o[4]=__half2float(__ushort_as_half((unsigned short)(u2&0xffffu)));
    o[5]=__half2float(__ushort_as_half((unsigned short)(u2>>16)));
    o[6]=__half2float(__ushort_as_half((unsigned short)(u3&0xffffu)));
    o[7]=__half2float(__ushort_as_half((unsigned short)(u3>>16)));
}

// B,C fp32 [b][n][t] -> fp16 combined records:
// BC[ ((b*32 + (t&31))*64 + (t>>5))*32 + n ]        (B at +n, C at +16+n)
// Per (step r, chunk c) a lane reads one contiguous 64 B record.
__global__ __launch_bounds__(256) void transpose_bc(
        const float* __restrict__ Bm, const float* __restrict__ Cm,
        __half* __restrict__ BC){
    const int q  = blockIdx.x*256 + threadIdx.x;   // 16384 float4 quads
    const int t0 = (q & 511) << 2;
    const int n  = (q >> 9) & 15;
    const int b  = q >> 13;
    const long i = (long)(b*NN + n)*LL + t0;
    const float4 bv = *(const float4*)(Bm + i);
    const float4 cv = *(const float4*)(Cm + i);
    const float bb[4]={bv.x,bv.y,bv.z,bv.w}, cc[4]={cv.x,cv.y,cv.z,cv.w};
#pragma unroll
    for (int j=0;j<4;++j){
        const int t = t0 + j;
        const long o = ((long)((b*CL + (t&31))*NCH + (t>>5)))*32 + n;
        BC[o]      = __float2half_rn(bb[j]);
        BC[o + 16] = __float2half_rn(cc[j]);
    }
}

// Block = 2 waves (128 thr); wave = 2 rows (same b, consecutive d) -> the
// two rows SHARE each B/C slab record (halves slab traffic vs 1 row/wave;
// fp16 records halve it again: 1.18 GB -> 295 MB through L1/L2).
// Lane = chunk (64 x 32 steps); thread owns 16 states x 2 rows.
// (delta,x) of both rows packed as 4 halfs in one 8 B LDS word, XOR-swizzled
// slot(r,c) = r*64 + (c^r)  -> hot-loop ds_read_b64 conflict-free.
// Grid 768 = exactly 3 blocks/CU (32 KB LDS each), zero tail.
__global__ __launch_bounds__(128, 2) void ssm_scan(
    const float* __restrict__ x, const float* __restrict__ delta,
    const float* __restrict__ A, const float* __restrict__ Dv,
    const float* __restrict__ z, const __half* __restrict__ BC,
    float* __restrict__ out)
{
    __shared__ float2 sdx[2][CL*64];   // 32 KB: halfs{d0,x0,d1,x1}; fp32 {y0,y1} after phase 3

    const int lane = threadIdx.x & 63;
    const int w    = threadIdx.x >> 6;
    const int row0 = blockIdx.x*4 + w*2;     // b*DM + d ; row1 = row0+1 (same b)
    const int b    = (row0 >= DM) ? 1 : 0;
    const int d0   = row0 - b*DM;
    float2* sw = sdx[w];

    const long base0 = (long)row0*LL;
    const long base1 = base0 + LL;
    const float* gd0 = delta + base0; const float* gx0 = x + base0;
    const float* gd1 = delta + base1; const float* gx1 = x + base1;

    // ---- stage packed (d,x) for both rows: coalesced float4 reads
    for (int k=0;k<LL;k+=256){
        const int t0 = k + lane*4;
        const float4 dv0 = *(const float4*)(gd0 + t0);
        const float4 xv0 = *(const float4*)(gx0 + t0);
        const float4 dv1 = *(const float4*)(gd1 + t0);
        const float4 xv1 = *(const float4*)(gx1 + t0);
        const float dd0[4]={dv0.x,dv0.y,dv0.z,dv0.w}, xx0[4]={xv0.x,xv0.y,xv0.z,xv0.w};
        const float dd1[4]={dv1.x,dv1.y,dv1.z,dv1.w}, xx1[4]={xv1.x,xv1.y,xv1.z,xv1.w};
#pragma unroll
        for (int j=0;j<4;++j){
            const int t = t0 + j, r = t & 31, c = t >> 5;
            float2 wd; wd.x = packdx(dd0[j], xx0[j]); wd.y = packdx(dd1[j], xx1[j]);
            sw[r*64 + (c^r)] = wd;
        }
    }

    float A20[NN], A21[NN];
#pragma unroll
    for (int n=0;n<NN;++n){
        A20[n] = A[d0*NN+n]     * LOG2E;
        A21[n] = A[(d0+1)*NN+n] * LOG2E;
    }

    // record for (b, r, lane) at half-index b*65536 + r*2048 + lane*32
    const __half* bc = BC + (long)b*65536 + lane*32;

    // ---- phase 1: local scan h0=0 -> G (both rows); P = exp2(A2*sum d)
    float G0[NN], G1[NN];
#pragma unroll
    for (int n=0;n<NN;++n){ G0[n]=0.f; G1[n]=0.f; }
    float ds0=0.f, ds1=0.f;
#pragma unroll 2
    for (int r=0;r<CL;++r){
        const float2 wd = sw[r*64 + (lane^r)];
        const float4* rec = (const float4*)(bc + (long)r*2048);
        float bb[16];
        unpack8(rec[0], bb); unpack8(rec[1], bb+8);
        float d_0,x_0,d_1,x_1;
        unpackdx(wd.x, d_0, x_0); unpackdx(wd.y, d_1, x_1);
        ds0 += d_0; ds1 += d_1;
        const float dx0 = d_0*x_0, dx1 = d_1*x_1;
#pragma unroll
        for (int n=0;n<NN;++n){
            const float e0 = fexp2(d_0*A20[n]);
            G0[n] = __builtin_fmaf(e0, G0[n], bb[n]*dx0);
            const float e1 = fexp2(d_1*A21[n]);
            G1[n] = __builtin_fmaf(e1, G1[n], bb[n]*dx1);
        }
    }

    // ---- phase 2: Kogge-Stone wave scan over chunks (both rows), shift
    float h0[NN], h1[NN];
    {
        float P0[NN], P1[NN];
#pragma unroll
        for (int n=0;n<NN;++n){ P0[n]=fexp2(ds0*A20[n]); P1[n]=fexp2(ds1*A21[n]); }
#pragma unroll
        for (int s=1;s<64;s<<=1){
#pragma unroll
            for (int n=0;n<NN;++n){
                const float pl0=__shfl_up(P0[n],s), gl0=__shfl_up(G0[n],s);
                const float pl1=__shfl_up(P1[n],s), gl1=__shfl_up(G1[n],s);
                if (lane >= s){
                    G0[n]=__builtin_fmaf(P0[n],gl0,G0[n]); P0[n]*=pl0;
                    G1[n]=__builtin_fmaf(P1[n],gl1,G1[n]); P1[n]*=pl1;
                }
            }
        }
#pragma unroll
        for (int n=0;n<NN;++n){
            const float g0=__shfl_up(G0[n],1), g1=__shfl_up(G1[n],1);
            h0[n] = (lane==0)?0.f:g0;
            h1[n] = (lane==0)?0.f:g1;
        }
    }

    // ---- phase 3: re-scan with true h_start; stash fp32 {y0+x0*D0, y1+x1*D1}
    const float Dd0 = Dv[d0], Dd1 = Dv[d0+1];
#pragma unroll 2
    for (int r=0;r<CL;++r){
        const int slot = r*64 + (lane^r);
        const float2 wd = sw[slot];
        const float4* rec = (const float4*)(bc + (long)r*2048);
        float bb[16], cc[16];
        unpack8(rec[0], bb); unpack8(rec[1], bb+8);
        unpack8(rec[2], cc); unpack8(rec[3], cc+8);
        float d_0,x_0,d_1,x_1;
        unpackdx(wd.x, d_0, x_0); unpackdx(wd.y, d_1, x_1);
        const float dx0 = d_0*x_0, dx1 = d_1*x_1;
        float ya0=0.f, yb0=0.f, ya1=0.f, yb1=0.f;
#pragma unroll
        for (int n=0;n<NN;n+=2){
            const float e0a = fexp2(d_0*A20[n]);
            h0[n]  =__builtin_fmaf(e0a,h0[n],  bb[n]*dx0);   ya0=__builtin_fmaf(h0[n],  cc[n],  ya0);
            const float e0b = fexp2(d_0*A20[n+1]);
            h0[n+1]=__builtin_fmaf(e0b,h0[n+1],bb[n+1]*dx0); yb0=__builtin_fmaf(h0[n+1],cc[n+1],yb0);
            const float e1a = fexp2(d_1*A21[n]);
            h1[n]  =__builtin_fmaf(e1a,h1[n],  bb[n]*dx1);   ya1=__builtin_fmaf(h1[n],  cc[n],  ya1);
            const float e1b = fexp2(d_1*A21[n+1]);
            h1[n+1]=__builtin_fmaf(e1b,h1[n+1],bb[n+1]*dx1); yb1=__builtin_fmaf(h1[n+1],cc[n+1],yb1);
        }
        float2 yo;
        yo.x = __builtin_fmaf(x_0, Dd0, ya0+yb0);
        yo.y = __builtin_fmaf(x_1, Dd1, ya1+yb1);
        sw[slot] = yo;                        // silu applied in epilogue
    }

    // ---- epilogue: stream z once per row, coalesced float4 in/out
    const float* gz0 = z + base0; const float* gz1 = z + base1;
    float* go0 = out + base0;     float* go1 = out + base1;
    for (int k=0;k<LL;k+=256){
        const int t0 = k + lane*4;
        const float4 zv0 = *(const float4*)(gz0 + t0);
        const float4 zv1 = *(const float4*)(gz1 + t0);
        const float zz0[4]={zv0.x,zv0.y,zv0.z,zv0.w}, zz1[4]={zv1.x,zv1.y,zv1.z,zv1.w};
        float o0[4], o1[4];
#pragma unroll
        for (int j=0;j<4;++j){
            const int t = t0 + j, r = t & 31, c = t >> 5;
            const float2 wd = sw[r*64 + (c^r)];
            const float s0 = frcp(1.f + fexp2(-zz0[j]*LOG2E));
            const float s1 = frcp(1.f + fexp2(-zz1[j]*LOG2E));
            o0[j] = wd.x * (zz0[j]*s0);
            o1[j] = wd.y * (zz1[j]*s1);
        }
        float4 a = {o0[0],o0[1],o0[2],o0[3]};
        float4 bq = {o1[0],o1[1],o1[2],o1[3]};
        *(float4*)(go0 + t0) = a;
        *(float4*)(go1 + t0) = bq;
    }
}

extern "C" void kernel_launch(void* const* d_in, const int* in_sizes, int n_in,
                              void* d_out, int out_size, void* d_ws, size_t ws_size,
                              hipStream_t stream) {
    const float* x     = (const float*)d_in[0];
    const float* delta = (const float*)d_in[1];
    const float* A     = (const float*)d_in[2];
    const float* B     = (const float*)d_in[3];
    const float* C     = (const float*)d_in[4];
    const float* Dv    = (const float*)d_in[5];
    const float* z     = (const float*)d_in[6];
    float* out = (float*)d_out;

    __half* BC = (__half*)d_ws;               // 131072 halfs = 256 KB

    transpose_bc<<<dim3(64), dim3(256), 0, stream>>>(B, C, BC);
    ssm_scan<<<dim3((2*DM)/4), dim3(128), 0, stream>>>(x, delta, A, Dv, z, BC, out);
}

// Round 9
// 156.379 us; speedup vs baseline: 1.2463x; 1.0681x over previous
//
#include <hip/hip_runtime.h>
#include <hip/hip_fp16.h>

#define LOG2E 1.44269504088896340736f
#define DM 1536
#define LL  2048
#define NN  16
#define NCH 128    // chunks per row (across 2 waves)
#define CL  16     // steps per chunk = LL / NCH

__device__ __forceinline__ float fexp2(float v){ return __builtin_amdgcn_exp2f(v); }
__device__ __forceinline__ float frcp(float v){ return __builtin_amdgcn_rcpf(v); }

__device__ __forceinline__ float packdx(float d, float x){
    unsigned u = (unsigned)__half_as_ushort(__float2half_rn(d))
               | ((unsigned)__half_as_ushort(__float2half_rn(x)) << 16);
    return __uint_as_float(u);
}
__device__ __forceinline__ void unpackdx(float f, float& d, float& x){
    const unsigned u = __float_as_uint(f);
    d = __half2float(__ushort_as_half((unsigned short)(u & 0xffffu)));
    x = __half2float(__ushort_as_half((unsigned short)(u >> 16)));
}
// float4 = 8 packed halfs -> 8 floats
__device__ __forceinline__ void unpack8(const float4 f, float* o){
    const unsigned u0=__float_as_uint(f.x), u1=__float_as_uint(f.y),
                   u2=__float_as_uint(f.z), u3=__float_as_uint(f.w);
    o[0]=__half2float(__ushort_as_half((unsigned short)(u0&0xffffu)));
    o[1]=__half2float(__ushort_as_half((unsigned short)(u0>>16)));
    o[2]=__half2float(__ushort_as_half((unsigned short)(u1&0xffffu)));
    o[3]=__half2float(__ushort_as_half((unsigned short)(u1>>16)));
    o[4]=__half2float(__ushort_as_half((unsigned short)(u2&0xffffu)));
    o[5]=__half2float(__ushort_as_half((unsigned short)(u2>>16)));
    o[6]=__half2float(__ushort_as_half((unsigned short)(u3&0xffffu)));
    o[7]=__half2float(__ushort_as_half((unsigned short)(u3>>16)));
}

// B,C fp32 [b][n][t] -> fp16 records: BC[((b*16 + (t&15))*128 + (t>>4))*32 + n]
// (B at +n, C at +16+n). Per (step r, chunk c) one contiguous 64 B record;
// per r the 128 chunks form one 8 KB slab read coalesced by 2 waves.
__global__ __launch_bounds__(256) void transpose_bc(
        const float* __restrict__ Bm, const float* __restrict__ Cm,
        __half* __restrict__ BC){
    const int q  = blockIdx.x*256 + threadIdx.x;   // 16384 float4 quads
    const int t0 = (q & 511) << 2;
    const int n  = (q >> 9) & 15;
    const int b  = q >> 13;
    const long i = (long)(b*NN + n)*LL + t0;
    const float4 bv = *(const float4*)(Bm + i);
    const float4 cv = *(const float4*)(Cm + i);
    const float bb[4]={bv.x,bv.y,bv.z,bv.w}, cc[4]={cv.x,cv.y,cv.z,cv.w};
#pragma unroll
    for (int j=0;j<4;++j){
        const int t = t0 + j;
        const long o = ((long)((b*CL + (t&15))*NCH + (t>>4)))*32 + n;
        BC[o]      = __float2half_rn(bb[j]);
        BC[o + 16] = __float2half_rn(cc[j]);
    }
}

// Block = 2 waves = ONE row-pair (2 consecutive d, same b). 128 chunks x 16
// steps; wave w owns chunks [w*64, w*64+64), lane = chunk within wave.
// Thread carries 16 states x 2 rows. Two-level scan: Kogge-Stone within each
// wave, wave-0 totals -> LDS -> one __syncthreads -> wave 1 composes
// h_start = fma(P_excl, G_total_w0, G_excl). Every B/C record is read by
// exactly one lane (traffic unchanged vs r8) but grid doubles to 1536 =
// 6 blocks/CU = 12 waves/CU. LDS 16 KB. delta/x packed half2, XOR-swizzled
// slot(r,c) = r*128 + (c^r); phase 3 overwrites slot with fp32 {y0,y1}.
__global__ __launch_bounds__(128, 3) void ssm_scan(
    const float* __restrict__ x, const float* __restrict__ delta,
    const float* __restrict__ A, const float* __restrict__ Dv,
    const float* __restrict__ z, const __half* __restrict__ BC,
    float* __restrict__ out)
{
    __shared__ float2 sdx[CL*NCH];     // 16 KB
    __shared__ float  wtot[2][2][NN];  // [P/G][row][n] from wave 0 lane 63

    const int lane = threadIdx.x & 63;
    const int w    = threadIdx.x >> 6;
    const int row0 = blockIdx.x*2;           // b*DM + d ; row1 = row0+1
    const int b    = (row0 >= DM) ? 1 : 0;
    const int d0   = row0 - b*DM;
    const int cmy  = w*64 + lane;            // my chunk (0..127)

    const long base0 = (long)row0*LL;
    const long base1 = base0 + LL;
    const float* gd0 = delta + base0; const float* gx0 = x + base0;
    const float* gd1 = delta + base1; const float* gx1 = x + base1;

    // ---- stage packed (d,x) for both rows; wave w covers t in [w*1024, +1024)
    for (int k=0;k<1024;k+=256){
        const int t0 = w*1024 + k + lane*4;
        const float4 dv0 = *(const float4*)(gd0 + t0);
        const float4 xv0 = *(const float4*)(gx0 + t0);
        const float4 dv1 = *(const float4*)(gd1 + t0);
        const float4 xv1 = *(const float4*)(gx1 + t0);
        const float dd0[4]={dv0.x,dv0.y,dv0.z,dv0.w}, xx0[4]={xv0.x,xv0.y,xv0.z,xv0.w};
        const float dd1[4]={dv1.x,dv1.y,dv1.z,dv1.w}, xx1[4]={xv1.x,xv1.y,xv1.z,xv1.w};
#pragma unroll
        for (int j=0;j<4;++j){
            const int t = t0 + j, r = t & 15, c = t >> 4;
            float2 wd; wd.x = packdx(dd0[j], xx0[j]); wd.y = packdx(dd1[j], xx1[j]);
            sdx[r*NCH + (c^r)] = wd;
        }
    }

    float A20[NN], A21[NN];
#pragma unroll
    for (int n=0;n<NN;++n){
        A20[n] = A[d0*NN+n]     * LOG2E;
        A21[n] = A[(d0+1)*NN+n] * LOG2E;
    }

    // record for (b, r, chunk cmy): BC + b*65536 + r*4096 + cmy*32 (halfs)
    const __half* bc = BC + (long)b*65536 + cmy*32;

    // ---- phase 1: local chunk scan h0=0 -> G (both rows); dsum -> P
    float G0[NN], G1[NN];
#pragma unroll
    for (int n=0;n<NN;++n){ G0[n]=0.f; G1[n]=0.f; }
    float ds0=0.f, ds1=0.f;
#pragma unroll 2
    for (int r=0;r<CL;++r){
        const float2 wd = sdx[r*NCH + (cmy^r)];
        const float4* rec = (const float4*)(bc + (long)r*4096);
        float bb[16];
        unpack8(rec[0], bb); unpack8(rec[1], bb+8);
        float d_0,x_0,d_1,x_1;
        unpackdx(wd.x, d_0, x_0); unpackdx(wd.y, d_1, x_1);
        ds0 += d_0; ds1 += d_1;
        const float dx0 = d_0*x_0, dx1 = d_1*x_1;
#pragma unroll
        for (int n=0;n<NN;++n){
            const float e0 = fexp2(d_0*A20[n]);
            G0[n] = __builtin_fmaf(e0, G0[n], bb[n]*dx0);
            const float e1 = fexp2(d_1*A21[n]);
            G1[n] = __builtin_fmaf(e1, G1[n], bb[n]*dx1);
        }
    }

    // ---- phase 2: two-level scan
    float h0[NN], h1[NN];
    {
        float P0[NN], P1[NN];
#pragma unroll
        for (int n=0;n<NN;++n){ P0[n]=fexp2(ds0*A20[n]); P1[n]=fexp2(ds1*A21[n]); }
        // inclusive Kogge-Stone within wave
#pragma unroll
        for (int s=1;s<64;s<<=1){
#pragma unroll
            for (int n=0;n<NN;++n){
                const float pl0=__shfl_up(P0[n],s), gl0=__shfl_up(G0[n],s);
                const float pl1=__shfl_up(P1[n],s), gl1=__shfl_up(G1[n],s);
                if (lane >= s){
                    G0[n]=__builtin_fmaf(P0[n],gl0,G0[n]); P0[n]*=pl0;
                    G1[n]=__builtin_fmaf(P1[n],gl1,G1[n]); P1[n]*=pl1;
                }
            }
        }
        // wave-0 totals -> LDS
        if (w==0 && lane==63){
#pragma unroll
            for (int n=0;n<NN;++n){
                wtot[0][0][n]=P0[n]; wtot[1][0][n]=G0[n];
                wtot[0][1][n]=P1[n]; wtot[1][1][n]=G1[n];
            }
        }
        __syncthreads();
        // exclusive within wave, then compose with wave-0 total (wave 1 only)
#pragma unroll
        for (int n=0;n<NN;++n){
            const float pe0=__shfl_up(P0[n],1), ge0=__shfl_up(G0[n],1);
            const float pe1=__shfl_up(P1[n],1), ge1=__shfl_up(G1[n],1);
            const float Px0 = (lane==0)?1.f:pe0, Gx0 = (lane==0)?0.f:ge0;
            const float Px1 = (lane==0)?1.f:pe1, Gx1 = (lane==0)?0.f:ge1;
            const float Gt0 = (w==0)?0.f:wtot[1][0][n];
            const float Gt1 = (w==0)?0.f:wtot[1][1][n];
            h0[n] = __builtin_fmaf(Px0, Gt0, Gx0);
            h1[n] = __builtin_fmaf(Px1, Gt1, Gx1);
        }
    }

    // ---- phase 3: re-scan with true h_start; stash fp32 {y0+x0*D0, y1+x1*D1}
    const float Dd0 = Dv[d0], Dd1 = Dv[d0+1];
#pragma unroll 2
    for (int r=0;r<CL;++r){
        const int slot = r*NCH + (cmy^r);
        const float2 wd = sdx[slot];
        const float4* rec = (const float4*)(bc + (long)r*4096);
        float bb[16], cc[16];
        unpack8(rec[0], bb); unpack8(rec[1], bb+8);
        unpack8(rec[2], cc); unpack8(rec[3], cc+8);
        float d_0,x_0,d_1,x_1;
        unpackdx(wd.x, d_0, x_0); unpackdx(wd.y, d_1, x_1);
        const float dx0 = d_0*x_0, dx1 = d_1*x_1;
        float ya0=0.f, yb0=0.f, ya1=0.f, yb1=0.f;
#pragma unroll
        for (int n=0;n<NN;n+=2){
            const float e0a = fexp2(d_0*A20[n]);
            h0[n]  =__builtin_fmaf(e0a,h0[n],  bb[n]*dx0);   ya0=__builtin_fmaf(h0[n],  cc[n],  ya0);
            const float e0b = fexp2(d_0*A20[n+1]);
            h0[n+1]=__builtin_fmaf(e0b,h0[n+1],bb[n+1]*dx0); yb0=__builtin_fmaf(h0[n+1],cc[n+1],yb0);
            const float e1a = fexp2(d_1*A21[n]);
            h1[n]  =__builtin_fmaf(e1a,h1[n],  bb[n]*dx1);   ya1=__builtin_fmaf(h1[n],  cc[n],  ya1);
            const float e1b = fexp2(d_1*A21[n+1]);
            h1[n+1]=__builtin_fmaf(e1b,h1[n+1],bb[n+1]*dx1); yb1=__builtin_fmaf(h1[n+1],cc[n+1],yb1);
        }
        float2 yo;
        yo.x = __builtin_fmaf(x_0, Dd0, ya0+yb0);
        yo.y = __builtin_fmaf(x_1, Dd1, ya1+yb1);
        sdx[slot] = yo;                        // silu applied in epilogue
    }

    // ---- epilogue: stream z once per row, coalesced float4 in/out
    const float* gz0 = z + base0; const float* gz1 = z + base1;
    float* go0 = out + base0;     float* go1 = out + base1;
    for (int k=0;k<1024;k+=256){
        const int t0 = w*1024 + k + lane*4;
        const float4 zv0 = *(const float4*)(gz0 + t0);
        const float4 zv1 = *(const float4*)(gz1 + t0);
        const float zz0[4]={zv0.x,zv0.y,zv0.z,zv0.w}, zz1[4]={zv1.x,zv1.y,zv1.z,zv1.w};
        float o0[4], o1[4];
#pragma unroll
        for (int j=0;j<4;++j){
            const int t = t0 + j, r = t & 15, c = t >> 4;
            const float2 wd = sdx[r*NCH + (c^r)];
            const float s0 = frcp(1.f + fexp2(-zz0[j]*LOG2E));
            const float s1 = frcp(1.f + fexp2(-zz1[j]*LOG2E));
            o0[j] = wd.x * (zz0[j]*s0);
            o1[j] = wd.y * (zz1[j]*s1);
        }
        float4 a  = {o0[0],o0[1],o0[2],o0[3]};
        float4 bq = {o1[0],o1[1],o1[2],o1[3]};
        *(float4*)(go0 + t0) = a;
        *(float4*)(go1 + t0) = bq;
    }
}

extern "C" void kernel_launch(void* const* d_in, const int* in_sizes, int n_in,
                              void* d_out, int out_size, void* d_ws, size_t ws_size,
                              hipStream_t stream) {
    const float* x     = (const float*)d_in[0];
    const float* delta = (const float*)d_in[1];
    const float* A     = (const float*)d_in[2];
    const float* B     = (const float*)d_in[3];
    const float* C     = (const float*)d_in[4];
    const float* Dv    = (const float*)d_in[5];
    const float* z     = (const float*)d_in[6];
    float* out = (float*)d_out;

    __half* BC = (__half*)d_ws;               // 131072 halfs = 256 KB

    transpose_bc<<<dim3(64), dim3(256), 0, stream>>>(B, C, BC);
    ssm_scan<<<dim3(DM), dim3(128), 0, stream>>>(x, delta, A, Dv, z, BC, out);
}